// Round 3
// baseline (798.151 us; speedup 1.0000x reference)
//
#include <hip/hip_runtime.h>
#include <math.h>

#define C 512
#define K 256
#define HW 160
#define NPIX (HW*HW)   // 25600
#define PW 162
#define EPS 1e-5f

typedef __attribute__((ext_vector_type(8))) short s16x8;
typedef __attribute__((ext_vector_type(4))) float f32x4;

__device__ __forceinline__ unsigned short f2bf(float f) {
    unsigned int u = __float_as_uint(f);
    u += 0x7fffu + ((u >> 16) & 1u);
    return (unsigned short)(u >> 16);
}

// ---------------- per-channel mean & max ----------------
__global__ void reduce_kernel(const float* __restrict__ x,
                              float* __restrict__ avg, float* __restrict__ mx) {
    int c = blockIdx.x;
    const float* xc = x + (size_t)c * NPIX;
    float s = 0.f, m = -INFINITY;
    for (int p = threadIdx.x; p < NPIX; p += 256) {
        float v = xc[p];
        s += v;
        m = fmaxf(m, v);
    }
    __shared__ float ss[256], sm[256];
    ss[threadIdx.x] = s; sm[threadIdx.x] = m;
    __syncthreads();
    for (int o = 128; o > 0; o >>= 1) {
        if (threadIdx.x < o) {
            ss[threadIdx.x] += ss[threadIdx.x + o];
            sm[threadIdx.x] = fmaxf(sm[threadIdx.x], sm[threadIdx.x + o]);
        }
        __syncthreads();
    }
    if (threadIdx.x == 0) {
        avg[c] = ss[0] / (float)NPIX;
        mx[c]  = sm[0];
    }
}

// ---------------- MLP + sigmoid + top-K selection ----------------
__global__ void mlp_select_kernel(const float* __restrict__ avg,
                                  const float* __restrict__ mx,
                                  const float* __restrict__ w_fc1,
                                  const float* __restrict__ w_fc2,
                                  float* __restrict__ scales_out,
                                  int* __restrict__ idx,
                                  int* __restrict__ pos) {
    __shared__ float s_avg[C], s_mx[C], s_h[K], s_scales[C];
    __shared__ int s_sel[C];
    int t = threadIdx.x;
    s_avg[t] = avg[t];
    s_mx[t]  = mx[t];
    __syncthreads();
    if (t < K) {
        float ha = 0.f, hm = 0.f;
        const float4* wr = (const float4*)(w_fc1 + (size_t)t * C);
        for (int c = 0; c < C / 4; c++) {
            float4 w = wr[c];
            ha += s_avg[4*c]*w.x + s_avg[4*c+1]*w.y + s_avg[4*c+2]*w.z + s_avg[4*c+3]*w.w;
            hm += s_mx[4*c]*w.x + s_mx[4*c+1]*w.y + s_mx[4*c+2]*w.z + s_mx[4*c+3]*w.w;
        }
        s_h[t] = fmaxf(ha, 0.f) + fmaxf(hm, 0.f);
    }
    __syncthreads();
    {
        float o = 0.f;
        const float4* wr = (const float4*)(w_fc2 + (size_t)t * K);
        for (int k = 0; k < K / 4; k++) {
            float4 w = wr[k];
            o += s_h[4*k]*w.x + s_h[4*k+1]*w.y + s_h[4*k+2]*w.z + s_h[4*k+3]*w.w;
        }
        float sc = 1.f / (1.f + expf(-o));
        s_scales[t] = sc;
        scales_out[t] = sc;
    }
    __syncthreads();
    {
        float v = s_scales[t];
        int rank = 0;
        for (int i = 0; i < C; i++) {
            float u = s_scales[i];
            rank += (u > v) || (u == v && i < t);
        }
        s_sel[t] = (rank < K) ? 1 : 0;
    }
    __syncthreads();
    {
        int p = 0;
        for (int i = 0; i < t; i++) p += s_sel[i];
        if (s_sel[t]) { idx[p] = t; pos[t] = p; }
        else pos[t] = -1;
    }
}

// ---------------- per-co affine for BN2 + bias fold ----------------
__global__ void affine_kernel(const float* __restrict__ b_dc1,
                              const float* __restrict__ g2, const float* __restrict__ b2,
                              const float* __restrict__ m2, const float* __restrict__ v2,
                              float* __restrict__ scale2, float* __restrict__ shift2) {
    int c = threadIdx.x;
    float s = g2[c] * rsqrtf(v2[c] + EPS);
    scale2[c] = s;
    shift2[c] = (b_dc1[c] - m2[c]) * s + b2[c];
}

// ---------------- combined 1x1 weight (768 eff. K) in bf16 ----------------
__global__ void wa_bf16_kernel(const float* __restrict__ w_dc1,
                               const float* __restrict__ scales,
                               const int* __restrict__ pos,
                               unsigned short* __restrict__ wA) {
    int co = blockIdx.x;
    const float* wr = w_dc1 + (size_t)co * 1024;
    for (int c = threadIdx.x; c < 768; c += 256) {
        float v;
        if (c < 512) {
            v = wr[c] * scales[c];
            int pp = pos[c];
            if (pp >= 0) v += wr[512 + pp];
        } else {
            v = wr[768 + (c - 512)];
        }
        wA[(size_t)co * 768 + c] = f2bf(v);
    }
}

// ---------------- repack conv3 weights: [co][ci][t] -> [t][co][ci] bf16 ----
__global__ void w3_kernel(const float* __restrict__ w_dc2, unsigned short* __restrict__ w3) {
    int co = blockIdx.x, t = blockIdx.y;
    for (int ci = threadIdx.x; ci < 512; ci += 256) {
        w3[((size_t)t * 512 + co) * 512 + ci] = f2bf(w_dc2[((size_t)co * 512 + ci) * 9 + t]);
    }
}

// ---------------- depthwise 3x3 + BN1 + ReLU -> x2 (fp32) ----------------
__global__ void dw_kernel(const float* __restrict__ x,
                          const int* __restrict__ idx,
                          const float* __restrict__ wch,
                          const float* __restrict__ g1,
                          const float* __restrict__ b1,
                          const float* __restrict__ m1,
                          const float* __restrict__ v1,
                          float* __restrict__ x2) {
    int k = blockIdx.y;
    int p = blockIdx.x * 256 + threadIdx.x;
    int c = idx[k];
    int y = p / HW, xx = p % HW;
    const float* xc = x + (size_t)c * NPIX;
    const float* wk = wch + k * 9;
    float acc = 0.f;
#pragma unroll
    for (int dy = 0; dy < 3; dy++) {
        int yy = y + dy - 1;
        if (yy < 0 || yy >= HW) continue;
#pragma unroll
        for (int dx = 0; dx < 3; dx++) {
            int xv = xx + dx - 1;
            if (xv < 0 || xv >= HW) continue;
            acc += xc[yy * HW + xv] * wk[dy * 3 + dx];
        }
    }
    float s = g1[k] * rsqrtf(v1[k] + EPS);
    float t = (acc - m1[k]) * s + b1[k];
    x2[(size_t)k * NPIX + p] = fmaxf(t, 0.f);
}

// ---------------- transpose x (512ch) and x2 (256ch) -> xcat_t[px][768] bf16 ----
__global__ void transpose_kernel(const float* __restrict__ x, const float* __restrict__ x2,
                                 unsigned short* __restrict__ xcat) {
    __shared__ float tile[32][33];
    int tx = threadIdx.x & 31, ty = threadIdx.x >> 5;
    int pbase = blockIdx.x * 32, cbase = blockIdx.y * 32;
#pragma unroll
    for (int j = 0; j < 4; j++) {
        int c = cbase + ty + j * 8;
        float v = (c < 512) ? x[(size_t)c * NPIX + pbase + tx]
                            : x2[(size_t)(c - 512) * NPIX + pbase + tx];
        tile[ty + j * 8][tx] = v;
    }
    __syncthreads();
#pragma unroll
    for (int j = 0; j < 4; j++) {
        int p = pbase + ty + j * 8;
        xcat[(size_t)p * 768 + cbase + tx] = f2bf(tile[tx][ty + j * 8]);
    }
}

// ---------------- zero only the hpad border (644 padded pixels) ----------------
__global__ void zero_border(unsigned short* __restrict__ hpad) {
    int t = blockIdx.x * 256 + threadIdx.x;   // 161*256 = 41216 = 644 px * 64 uint4
    int pix = t >> 6;
    int pos;
    if (pix < 162)      pos = pix;                         // row 0
    else if (pix < 324) pos = 161 * PW + (pix - 162);      // row 161
    else {
        int r = pix - 324;                                  // cols 0/161, rows 1..160
        pos = (1 + (r >> 1)) * PW + ((r & 1) ? 161 : 0);
    }
    *(uint4*)&hpad[(size_t)pos * 512 + (t & 63) * 8] = make_uint4(0u, 0u, 0u, 0u);
}

// ---------------- conv1 (1x1, K=768) via MFMA -> hpad_t bf16 ----------------
__global__ __launch_bounds__(256) void conv1_mfma(const unsigned short* __restrict__ xcat,
        const unsigned short* __restrict__ wA,
        const float* __restrict__ scale2, const float* __restrict__ shift2,
        unsigned short* __restrict__ hpad) {
    __shared__ short Al[160 * 32];
    __shared__ short Bl[128 * 32];
    int y = blockIdx.x, co0 = blockIdx.y * 128;
    int tid = threadIdx.x, lane = tid & 63, wv = tid >> 6;
    int wm = wv & 1, wn = wv >> 1;
    int l15 = lane & 15, q = lane >> 4;
    int sw0 = (q ^ ((l15 >> 1) & 3)) << 4;   // swizzled read byte-offset
    f32x4 acc[5][4] = {};
    uint4 aR[3], bR[2];
    // phase 0 prefetch
#pragma unroll
    for (int l = 0; l < 3; l++) {
        int c = tid + 256 * l;
        if (c < 640) aR[l] = *(const uint4*)&xcat[(size_t)(y * HW + (c >> 2)) * 768 + (c & 3) * 8];
    }
#pragma unroll
    for (int l = 0; l < 2; l++) {
        int c = tid + 256 * l;
        bR[l] = *(const uint4*)&wA[(size_t)(co0 + (c >> 2)) * 768 + (c & 3) * 8];
    }
    for (int ph = 0; ph < 24; ph++) {
        // commit staged registers to LDS (swizzled granules)
#pragma unroll
        for (int l = 0; l < 3; l++) {
            int c = tid + 256 * l;
            if (c < 640) {
                int row = c >> 2, g = c & 3;
                *(uint4*)((char*)Al + row * 64 + ((g ^ ((row >> 1) & 3)) << 4)) = aR[l];
            }
        }
#pragma unroll
        for (int l = 0; l < 2; l++) {
            int c = tid + 256 * l;
            int row = c >> 2, g = c & 3;
            *(uint4*)((char*)Bl + row * 64 + ((g ^ ((row >> 1) & 3)) << 4)) = bR[l];
        }
        __syncthreads();
        // prefetch next phase into registers (latency hidden under MFMA below)
        if (ph < 23) {
            int kc = (ph + 1) * 32;
#pragma unroll
            for (int l = 0; l < 3; l++) {
                int c = tid + 256 * l;
                if (c < 640) aR[l] = *(const uint4*)&xcat[(size_t)(y * HW + (c >> 2)) * 768 + kc + (c & 3) * 8];
            }
#pragma unroll
            for (int l = 0; l < 2; l++) {
                int c = tid + 256 * l;
                bR[l] = *(const uint4*)&wA[(size_t)(co0 + (c >> 2)) * 768 + kc + (c & 3) * 8];
            }
        }
        s16x8 af[5], bfr[4];
#pragma unroll
        for (int i = 0; i < 5; i++)
            af[i] = *(const s16x8*)((const char*)Al + (wm * 80 + i * 16 + l15) * 64 + sw0);
#pragma unroll
        for (int j = 0; j < 4; j++)
            bfr[j] = *(const s16x8*)((const char*)Bl + (wn * 64 + j * 16 + l15) * 64 + sw0);
#pragma unroll
        for (int i = 0; i < 5; i++)
#pragma unroll
            for (int j = 0; j < 4; j++)
                acc[i][j] = __builtin_amdgcn_mfma_f32_16x16x32_bf16(af[i], bfr[j], acc[i][j], 0, 0, 0);
        __syncthreads();
    }
#pragma unroll
    for (int j = 0; j < 4; j++) {
        int n = co0 + wn * 64 + j * 16 + l15;
        float s = scale2[n], c0 = shift2[n];
#pragma unroll
        for (int i = 0; i < 5; i++) {
            int xb = wm * 80 + i * 16 + q * 4;
#pragma unroll
            for (int r = 0; r < 4; r++) {
                size_t pp = (size_t)(y + 1) * PW + (xb + r + 1);
                hpad[pp * 512 + n] = f2bf(acc[i][j][r] * s + c0);
            }
        }
    }
}

// ---------------- conv3 (3x3, K=4608) via MFMA -> out fp32 ----------------
__global__ __launch_bounds__(256) void conv3_mfma(const unsigned short* __restrict__ hpad,
        const unsigned short* __restrict__ w3,
        const float* __restrict__ bias, float* __restrict__ out) {
    __shared__ short Al[162 * 32];
    __shared__ short Bl[3 * 128 * 32];
    int y = blockIdx.x, co0 = blockIdx.y * 128;
    int tid = threadIdx.x, lane = tid & 63, wv = tid >> 6;
    int wm = wv & 1, wn = wv >> 1;
    int l15 = lane & 15, q = lane >> 4;
    int swA[3];
#pragma unroll
    for (int dx = 0; dx < 3; dx++) swA[dx] = (q ^ (((l15 + dx) >> 1) & 3)) << 4;
    int swB = (q ^ ((l15 >> 1) & 3)) << 4;
    f32x4 acc[5][4] = {};
    uint4 aR[3], bR[6];
    // phase 0 prefetch (dy=0, kc=0)
#pragma unroll
    for (int l = 0; l < 3; l++) {
        int c = tid + 256 * l;
        if (c < 648) aR[l] = *(const uint4*)&hpad[((size_t)y * PW + (c >> 2)) * 512 + (c & 3) * 8];
    }
#pragma unroll
    for (int l = 0; l < 6; l++) {
        int c = tid + 256 * l;
        int tt = c >> 9, n = (c >> 2) & 127, g = c & 3;
        bR[l] = *(const uint4*)&w3[((size_t)(tt * 512) + co0 + n) * 512 + g * 8];
    }
    for (int ph = 0; ph < 48; ph++) {
        // commit staged registers to LDS (swizzled granules)
#pragma unroll
        for (int l = 0; l < 3; l++) {
            int c = tid + 256 * l;
            if (c < 648) {
                int row = c >> 2, g = c & 3;
                *(uint4*)((char*)Al + row * 64 + ((g ^ ((row >> 1) & 3)) << 4)) = aR[l];
            }
        }
#pragma unroll
        for (int l = 0; l < 6; l++) {
            int c = tid + 256 * l;
            int tt = c >> 9, n = (c >> 2) & 127, g = c & 3;
            *(uint4*)((char*)Bl + tt * 8192 + n * 64 + ((g ^ ((n >> 1) & 3)) << 4)) = bR[l];
        }
        __syncthreads();
        // prefetch next phase
        if (ph < 47) {
            int pn = ph + 1;
            int dy = pn >> 4, kc = (pn & 15) * 32;
            size_t arow = (size_t)(y + dy) * PW;
#pragma unroll
            for (int l = 0; l < 3; l++) {
                int c = tid + 256 * l;
                if (c < 648) aR[l] = *(const uint4*)&hpad[(arow + (c >> 2)) * 512 + kc + (c & 3) * 8];
            }
            const unsigned short* w3d = w3 + (size_t)dy * (3 * 512 * 512);
#pragma unroll
            for (int l = 0; l < 6; l++) {
                int c = tid + 256 * l;
                int tt = c >> 9, n = (c >> 2) & 127, g = c & 3;
                bR[l] = *(const uint4*)&w3d[((size_t)(tt * 512) + co0 + n) * 512 + kc + g * 8];
            }
        }
        // compute: 3 dx taps x 5x4 MFMA
#pragma unroll
        for (int dx = 0; dx < 3; dx++) {
            s16x8 af[5], bfr[4];
#pragma unroll
            for (int i = 0; i < 5; i++) {
                int m = wm * 80 + i * 16 + l15 + dx;
                af[i] = *(const s16x8*)((const char*)Al + m * 64 + swA[dx]);
            }
#pragma unroll
            for (int j = 0; j < 4; j++) {
                int n = wn * 64 + j * 16 + l15;
                bfr[j] = *(const s16x8*)((const char*)Bl + dx * 8192 + n * 64 + swB);
            }
#pragma unroll
            for (int i = 0; i < 5; i++)
#pragma unroll
                for (int j = 0; j < 4; j++)
                    acc[i][j] = __builtin_amdgcn_mfma_f32_16x16x32_bf16(af[i], bfr[j], acc[i][j], 0, 0, 0);
        }
        __syncthreads();
    }
#pragma unroll
    for (int j = 0; j < 4; j++) {
        int n = co0 + wn * 64 + j * 16 + l15;
        float b = bias[n];
        float* op = out + (size_t)n * NPIX + y * HW;
#pragma unroll
        for (int i = 0; i < 5; i++) {
            int xb = wm * 80 + i * 16 + q * 4;
            float4 v;
            v.x = fmaxf(acc[i][j][0] + b, 0.f);
            v.y = fmaxf(acc[i][j][1] + b, 0.f);
            v.z = fmaxf(acc[i][j][2] + b, 0.f);
            v.w = fmaxf(acc[i][j][3] + b, 0.f);
            *(float4*)&op[xb] = v;
        }
    }
}

extern "C" void kernel_launch(void* const* d_in, const int* in_sizes, int n_in,
                              void* d_out, int out_size, void* d_ws, size_t ws_size,
                              hipStream_t stream) {
    const float* x      = (const float*)d_in[0];
    const float* w_fc1  = (const float*)d_in[1];
    const float* w_fc2  = (const float*)d_in[2];
    const float* w_ch   = (const float*)d_in[3];
    const float* bn1_g  = (const float*)d_in[4];
    const float* bn1_b  = (const float*)d_in[5];
    const float* bn1_m  = (const float*)d_in[6];
    const float* bn1_v  = (const float*)d_in[7];
    const float* w_dc1  = (const float*)d_in[8];
    const float* b_dc1  = (const float*)d_in[9];
    const float* bn2_g  = (const float*)d_in[10];
    const float* bn2_b  = (const float*)d_in[11];
    const float* bn2_m  = (const float*)d_in[12];
    const float* bn2_v  = (const float*)d_in[13];
    const float* w_dc2  = (const float*)d_in[14];
    const float* b_dc2  = (const float*)d_in[15];
    float* out = (float*)d_out;

    char* ws = (char*)d_ws;
    float* avg    = (float*)(ws + 0);
    float* mx     = (float*)(ws + 2048);
    float* scales = (float*)(ws + 4096);
    int*   idx    = (int*)  (ws + 6144);
    int*   pos    = (int*)  (ws + 7168);
    float* scale2 = (float*)(ws + 9216);
    float* shift2 = (float*)(ws + 11264);
    unsigned short* wA   = (unsigned short*)(ws + 16384);              // 512*768*2  = 786432
    unsigned short* w3   = (unsigned short*)(ws + 802816);             // 9*512*512*2 = 4718592
    float*          x2   = (float*)         (ws + 5521408);            // 256*25600*4 = 26214400
    unsigned short* xcat = (unsigned short*)(ws + 31735808);           // 25600*768*2 = 39321600
    unsigned short* hpad = (unsigned short*)(ws + 71057408);           // 162*162*512*2 = 26873856

    reduce_kernel<<<C, 256, 0, stream>>>(x, avg, mx);
    mlp_select_kernel<<<1, C, 0, stream>>>(avg, mx, w_fc1, w_fc2, scales, idx, pos);
    affine_kernel<<<1, C, 0, stream>>>(b_dc1, bn2_g, bn2_b, bn2_m, bn2_v, scale2, shift2);
    wa_bf16_kernel<<<C, 256, 0, stream>>>(w_dc1, scales, pos, wA);
    w3_kernel<<<dim3(C, 9), 256, 0, stream>>>(w_dc2, w3);
    zero_border<<<161, 256, 0, stream>>>(hpad);
    dw_kernel<<<dim3(NPIX / 256, K), 256, 0, stream>>>(x, idx, w_ch, bn1_g, bn1_b, bn1_m, bn1_v, x2);
    transpose_kernel<<<dim3(NPIX / 32, 24), 256, 0, stream>>>(x, x2, xcat);
    conv1_mfma<<<dim3(HW, 4), 256, 0, stream>>>(xcat, wA, scale2, shift2, hpad);
    conv3_mfma<<<dim3(HW, 4), 256, 0, stream>>>(hpad, w3, b_dc2, out);
}

// Round 4
// 476.734 us; speedup vs baseline: 1.6742x; 1.6742x over previous
//
#include <hip/hip_runtime.h>
#include <math.h>

#define C 512
#define K 256
#define HW 160
#define NPIX (HW*HW)   // 25600
#define PW 162
#define EPS 1e-5f

typedef __attribute__((ext_vector_type(8))) short s16x8;
typedef __attribute__((ext_vector_type(16))) float f32x16;

__device__ __forceinline__ unsigned short f2bf(float f) {
    unsigned int u = __float_as_uint(f);
    u += 0x7fffu + ((u >> 16) & 1u);
    return (unsigned short)(u >> 16);
}

// async global->LDS 16B: LDS dest = wave-uniform base + lane*16
__device__ __forceinline__ void ldg_lds16(const void* g, void* l) {
    __builtin_amdgcn_global_load_lds((const __attribute__((address_space(1))) unsigned int*)g,
                                     (__attribute__((address_space(3))) unsigned int*)l, 16, 0, 0);
}

// ---------------- per-channel mean & max ----------------
__global__ void reduce_kernel(const float* __restrict__ x,
                              float* __restrict__ avg, float* __restrict__ mx) {
    int c = blockIdx.x;
    const float* xc = x + (size_t)c * NPIX;
    float s = 0.f, m = -INFINITY;
    for (int p = threadIdx.x; p < NPIX; p += 256) {
        float v = xc[p];
        s += v;
        m = fmaxf(m, v);
    }
    __shared__ float ss[256], sm[256];
    ss[threadIdx.x] = s; sm[threadIdx.x] = m;
    __syncthreads();
    for (int o = 128; o > 0; o >>= 1) {
        if (threadIdx.x < o) {
            ss[threadIdx.x] += ss[threadIdx.x + o];
            sm[threadIdx.x] = fmaxf(sm[threadIdx.x], sm[threadIdx.x + o]);
        }
        __syncthreads();
    }
    if (threadIdx.x == 0) {
        avg[c] = ss[0] / (float)NPIX;
        mx[c]  = sm[0];
    }
}

// ---------------- MLP + sigmoid + top-K selection ----------------
__global__ void mlp_select_kernel(const float* __restrict__ avg,
                                  const float* __restrict__ mx,
                                  const float* __restrict__ w_fc1,
                                  const float* __restrict__ w_fc2,
                                  float* __restrict__ scales_out,
                                  int* __restrict__ idx,
                                  int* __restrict__ pos) {
    __shared__ float s_avg[C], s_mx[C], s_h[K], s_scales[C];
    __shared__ int s_sel[C];
    int t = threadIdx.x;
    s_avg[t] = avg[t];
    s_mx[t]  = mx[t];
    __syncthreads();
    if (t < K) {
        float ha = 0.f, hm = 0.f;
        const float4* wr = (const float4*)(w_fc1 + (size_t)t * C);
        for (int c = 0; c < C / 4; c++) {
            float4 w = wr[c];
            ha += s_avg[4*c]*w.x + s_avg[4*c+1]*w.y + s_avg[4*c+2]*w.z + s_avg[4*c+3]*w.w;
            hm += s_mx[4*c]*w.x + s_mx[4*c+1]*w.y + s_mx[4*c+2]*w.z + s_mx[4*c+3]*w.w;
        }
        s_h[t] = fmaxf(ha, 0.f) + fmaxf(hm, 0.f);
    }
    __syncthreads();
    {
        float o = 0.f;
        const float4* wr = (const float4*)(w_fc2 + (size_t)t * K);
        for (int k = 0; k < K / 4; k++) {
            float4 w = wr[k];
            o += s_h[4*k]*w.x + s_h[4*k+1]*w.y + s_h[4*k+2]*w.z + s_h[4*k+3]*w.w;
        }
        float sc = 1.f / (1.f + expf(-o));
        s_scales[t] = sc;
        scales_out[t] = sc;
    }
    __syncthreads();
    {
        float v = s_scales[t];
        int rank = 0;
        for (int i = 0; i < C; i++) {
            float u = s_scales[i];
            rank += (u > v) || (u == v && i < t);
        }
        s_sel[t] = (rank < K) ? 1 : 0;
    }
    __syncthreads();
    {
        int p = 0;
        for (int i = 0; i < t; i++) p += s_sel[i];
        if (s_sel[t]) { idx[p] = t; pos[t] = p; }
        else pos[t] = -1;
    }
}

// ---------------- per-co affine for BN2 + bias fold ----------------
__global__ void affine_kernel(const float* __restrict__ b_dc1,
                              const float* __restrict__ g2, const float* __restrict__ b2,
                              const float* __restrict__ m2, const float* __restrict__ v2,
                              float* __restrict__ scale2, float* __restrict__ shift2) {
    int c = threadIdx.x;
    float s = g2[c] * rsqrtf(v2[c] + EPS);
    scale2[c] = s;
    shift2[c] = (b_dc1[c] - m2[c]) * s + b2[c];
}

// ---------------- combined 1x1 weight (768 eff. K) in bf16 ----------------
__global__ void wa_bf16_kernel(const float* __restrict__ w_dc1,
                               const float* __restrict__ scales,
                               const int* __restrict__ pos,
                               unsigned short* __restrict__ wA) {
    int co = blockIdx.x;
    const float* wr = w_dc1 + (size_t)co * 1024;
    for (int c = threadIdx.x; c < 768; c += 256) {
        float v;
        if (c < 512) {
            v = wr[c] * scales[c];
            int pp = pos[c];
            if (pp >= 0) v += wr[512 + pp];
        } else {
            v = wr[768 + (c - 512)];
        }
        wA[(size_t)co * 768 + c] = f2bf(v);
    }
}

// ---------------- repack conv3 weights: [co][ci][t] -> [t][co][ci] bf16 ----
__global__ void w3_kernel(const float* __restrict__ w_dc2, unsigned short* __restrict__ w3) {
    int co = blockIdx.x, t = blockIdx.y;
    for (int ci = threadIdx.x; ci < 512; ci += 256) {
        w3[((size_t)t * 512 + co) * 512 + ci] = f2bf(w_dc2[((size_t)co * 512 + ci) * 9 + t]);
    }
}

// ---------------- depthwise 3x3 + BN1 + ReLU -> x2 (fp32) ----------------
__global__ void dw_kernel(const float* __restrict__ x,
                          const int* __restrict__ idx,
                          const float* __restrict__ wch,
                          const float* __restrict__ g1,
                          const float* __restrict__ b1,
                          const float* __restrict__ m1,
                          const float* __restrict__ v1,
                          float* __restrict__ x2) {
    int k = blockIdx.y;
    int p = blockIdx.x * 256 + threadIdx.x;
    int c = idx[k];
    int y = p / HW, xx = p % HW;
    const float* xc = x + (size_t)c * NPIX;
    const float* wk = wch + k * 9;
    float acc = 0.f;
#pragma unroll
    for (int dy = 0; dy < 3; dy++) {
        int yy = y + dy - 1;
        if (yy < 0 || yy >= HW) continue;
#pragma unroll
        for (int dx = 0; dx < 3; dx++) {
            int xv = xx + dx - 1;
            if (xv < 0 || xv >= HW) continue;
            acc += xc[yy * HW + xv] * wk[dy * 3 + dx];
        }
    }
    float s = g1[k] * rsqrtf(v1[k] + EPS);
    float t = (acc - m1[k]) * s + b1[k];
    x2[(size_t)k * NPIX + p] = fmaxf(t, 0.f);
}

// ---------------- transpose x (512ch) and x2 (256ch) -> xcat_t[px][768] bf16 ----
__global__ void transpose_kernel(const float* __restrict__ x, const float* __restrict__ x2,
                                 unsigned short* __restrict__ xcat) {
    __shared__ float tile[32][33];
    int tx = threadIdx.x & 31, ty = threadIdx.x >> 5;
    int pbase = blockIdx.x * 32, cbase = blockIdx.y * 32;
#pragma unroll
    for (int j = 0; j < 4; j++) {
        int c = cbase + ty + j * 8;
        float v = (c < 512) ? x[(size_t)c * NPIX + pbase + tx]
                            : x2[(size_t)(c - 512) * NPIX + pbase + tx];
        tile[ty + j * 8][tx] = v;
    }
    __syncthreads();
#pragma unroll
    for (int j = 0; j < 4; j++) {
        int p = pbase + ty + j * 8;
        xcat[(size_t)p * 768 + cbase + tx] = f2bf(tile[tx][ty + j * 8]);
    }
}

// ---------------- zero only the hpad border (644 padded pixels) ----------------
__global__ void zero_border(unsigned short* __restrict__ hpad) {
    int t = blockIdx.x * 256 + threadIdx.x;   // 161*256 = 41216 = 644 px * 64 uint4
    int pix = t >> 6;
    int pos;
    if (pix < 162)      pos = pix;                         // row 0
    else if (pix < 324) pos = 161 * PW + (pix - 162);      // row 161
    else {
        int r = pix - 324;                                  // cols 0/161, rows 1..160
        pos = (1 + (r >> 1)) * PW + ((r & 1) ? 161 : 0);
    }
    *(uint4*)&hpad[(size_t)pos * 512 + (t & 63) * 8] = make_uint4(0u, 0u, 0u, 0u);
}

// ---------------- conv1 (1x1, K=768), 32x32x16 MFMA, global_load_lds staging ----
// block = 128 thr (2 waves); wave tile = 160 px x 64 co; grid (160, 4)
__global__ __launch_bounds__(128, 2) void conv1_mfma(const unsigned short* __restrict__ xcat,
        const unsigned short* __restrict__ wA,
        const float* __restrict__ scale2, const float* __restrict__ shift2,
        unsigned short* __restrict__ hpad) {
    __shared__ unsigned short Al[640 * 8];   // 160 px x 32 ch
    __shared__ unsigned short Bl[512 * 8];   // 128 co x 32 ch
    int y = blockIdx.x, co0 = blockIdx.y * 128;
    int tid = threadIdx.x, lane = tid & 63, wv = tid >> 6;
    int l31 = lane & 31, q = lane >> 5;
    f32x16 acc[5][2] = {};
    // per-thread-constant staging params (see swizzle algebra in comments below)
    int svA = tid >> 2, sjA = tid & 3;
    int sgA = sjA ^ ((svA >> 1) & 3);        // global granule to fetch for A
    for (int kc = 0; kc < 24; kc++) {
        __syncthreads();
        // --- A stage: 640 granules (160 px x 4), 5 rounds ---
        {
            const unsigned short* ab = xcat + ((size_t)y * HW) * 768 + kc * 32;
#pragma unroll
            for (int r = 0; r < 5; r++) {
                int px = r * 32 + svA;
                ldg_lds16(ab + (size_t)px * 768 + sgA * 8, &Al[(r * 128 + wv * 64) * 8]);
            }
        }
        // --- B stage: 512 granules (128 co x 4), 4 rounds ---
        {
            const unsigned short* bb = wA + (size_t)co0 * 768 + kc * 32;
#pragma unroll
            for (int r = 0; r < 4; r++) {
                int co = r * 32 + svA;
                ldg_lds16(bb + (size_t)co * 768 + sgA * 8, &Bl[(r * 128 + wv * 64) * 8]);
            }
        }
        __syncthreads();
        // --- compute: 2 k16 steps x (5 A x 2 B) ---
#pragma unroll
        for (int s = 0; s < 2; s++) {
            int g0 = s * 2 + q;
            s16x8 bf[2], af[5];
            const char* bbase = (const char*)Bl + wv * 4096 + l31 * 64 + ((g0 ^ ((l31 >> 1) & 3)) << 4);
#pragma unroll
            for (int j = 0; j < 2; j++) bf[j] = *(const s16x8*)(bbase + j * 2048);
            const char* abase = (const char*)Al + l31 * 64 + ((g0 ^ ((l31 >> 1) & 3)) << 4);
#pragma unroll
            for (int i = 0; i < 5; i++) af[i] = *(const s16x8*)(abase + i * 2048);
#pragma unroll
            for (int i = 0; i < 5; i++)
#pragma unroll
                for (int j = 0; j < 2; j++)
                    acc[i][j] = __builtin_amdgcn_mfma_f32_32x32x16_bf16(af[i], bf[j], acc[i][j], 0, 0, 0);
        }
    }
    // epilogue: C/D layout col=lane&31, row=(reg&3)+8*(reg>>2)+4*q
#pragma unroll
    for (int j = 0; j < 2; j++) {
        int co = co0 + wv * 64 + j * 32 + l31;
        float s2 = scale2[co], sh = shift2[co];
#pragma unroll
        for (int i = 0; i < 5; i++) {
#pragma unroll
            for (int rg = 0; rg < 4; rg++) {
#pragma unroll
                for (int t = 0; t < 4; t++) {
                    int px = i * 32 + t + rg * 8 + q * 4;
                    size_t pp = (size_t)(y + 1) * PW + px + 1;
                    hpad[pp * 512 + co] = f2bf(acc[i][j][rg * 4 + t] * s2 + sh);
                }
            }
        }
    }
}

// ---------------- conv3 (3x3, K=4608), 32x32x16 MFMA, global_load_lds staging ----
// block = 128 thr (2 waves); wave tile = 160 px x 64 co; grid (160, 4)
__global__ __launch_bounds__(128, 2) void conv3_mfma(const unsigned short* __restrict__ hpad,
        const unsigned short* __restrict__ w3,
        const float* __restrict__ bias, float* __restrict__ out) {
    __shared__ unsigned short Al[648 * 8];    // 162 px x 32 ch
    __shared__ unsigned short Bl[1536 * 8];   // 3 dx x 128 co x 32 ch
    int y = blockIdx.x, co0 = blockIdx.y * 128;
    int tid = threadIdx.x, lane = tid & 63, wv = tid >> 6;
    int l31 = lane & 31, q = lane >> 5;
    f32x16 acc[5][2] = {};
    int svA = tid >> 2, sjA = tid & 3;
    int sgA = sjA ^ ((svA >> 1) & 3);
    for (int dy = 0; dy < 3; dy++) {
        for (int kc = 0; kc < 16; kc++) {
            __syncthreads();
            // --- A stage: padded row y+dy, 648 granules, 6 rounds (last partial) ---
            {
                const unsigned short* ab = hpad + ((size_t)(y + dy) * PW) * 512 + kc * 32;
#pragma unroll
                for (int r = 0; r < 6; r++) {
                    int gi = r * 128 + tid;
                    if (gi < 648) {
                        int px = r * 32 + svA;
                        ldg_lds16(ab + (size_t)px * 512 + sgA * 8, &Al[(r * 128 + wv * 64) * 8]);
                    }
                }
            }
            // --- B stage: 3 taps x 128 co, 1536 granules, 12 rounds ---
            {
                const unsigned short* bb = w3 + ((size_t)(dy * 3) * 512 + co0) * 512 + kc * 32;
#pragma unroll
                for (int r = 0; r < 12; r++) {
                    int tt = r >> 2, co = (r & 3) * 32 + svA;
                    ldg_lds16(bb + ((size_t)tt * 512 + co) * 512 + sgA * 8,
                              &Bl[(r * 128 + wv * 64) * 8]);
                }
            }
            __syncthreads();
            // --- compute: 3 dx x 2 k16 x (5 A x 2 B) ---
#pragma unroll
            for (int dx = 0; dx < 3; dx++) {
#pragma unroll
                for (int s = 0; s < 2; s++) {
                    int g0 = s * 2 + q;
                    s16x8 bf[2], af[5];
                    const char* bbase = (const char*)Bl + dx * 8192 + wv * 4096 + l31 * 64
                                        + ((g0 ^ ((l31 >> 1) & 3)) << 4);
#pragma unroll
                    for (int j = 0; j < 2; j++) bf[j] = *(const s16x8*)(bbase + j * 2048);
                    int pl = dx + l31;   // (px>>1)&3 == ((dx+l31)>>1)&3 since i*32 ≡ 0 mod 8
                    const char* abase = (const char*)Al + pl * 64
                                        + ((g0 ^ ((pl >> 1) & 3)) << 4);
#pragma unroll
                    for (int i = 0; i < 5; i++) af[i] = *(const s16x8*)(abase + i * 2048);
#pragma unroll
                    for (int i = 0; i < 5; i++)
#pragma unroll
                        for (int j = 0; j < 2; j++)
                            acc[i][j] = __builtin_amdgcn_mfma_f32_32x32x16_bf16(af[i], bf[j], acc[i][j], 0, 0, 0);
                }
            }
        }
    }
    // epilogue: float4 stores (regs rg*4..rg*4+3 are 4 consecutive px)
#pragma unroll
    for (int j = 0; j < 2; j++) {
        int co = co0 + wv * 64 + j * 32 + l31;
        float b = bias[co];
        float* op = out + (size_t)co * NPIX + y * HW;
#pragma unroll
        for (int i = 0; i < 5; i++) {
#pragma unroll
            for (int rg = 0; rg < 4; rg++) {
                int px = i * 32 + rg * 8 + q * 4;
                float4 v;
                v.x = fmaxf(acc[i][j][rg * 4 + 0] + b, 0.f);
                v.y = fmaxf(acc[i][j][rg * 4 + 1] + b, 0.f);
                v.z = fmaxf(acc[i][j][rg * 4 + 2] + b, 0.f);
                v.w = fmaxf(acc[i][j][rg * 4 + 3] + b, 0.f);
                *(float4*)&op[px] = v;
            }
        }
    }
}

extern "C" void kernel_launch(void* const* d_in, const int* in_sizes, int n_in,
                              void* d_out, int out_size, void* d_ws, size_t ws_size,
                              hipStream_t stream) {
    const float* x      = (const float*)d_in[0];
    const float* w_fc1  = (const float*)d_in[1];
    const float* w_fc2  = (const float*)d_in[2];
    const float* w_ch   = (const float*)d_in[3];
    const float* bn1_g  = (const float*)d_in[4];
    const float* bn1_b  = (const float*)d_in[5];
    const float* bn1_m  = (const float*)d_in[6];
    const float* bn1_v  = (const float*)d_in[7];
    const float* w_dc1  = (const float*)d_in[8];
    const float* b_dc1  = (const float*)d_in[9];
    const float* bn2_g  = (const float*)d_in[10];
    const float* bn2_b  = (const float*)d_in[11];
    const float* bn2_m  = (const float*)d_in[12];
    const float* bn2_v  = (const float*)d_in[13];
    const float* w_dc2  = (const float*)d_in[14];
    const float* b_dc2  = (const float*)d_in[15];
    float* out = (float*)d_out;

    char* ws = (char*)d_ws;
    float* avg    = (float*)(ws + 0);
    float* mx     = (float*)(ws + 2048);
    float* scales = (float*)(ws + 4096);
    int*   idx    = (int*)  (ws + 6144);
    int*   pos    = (int*)  (ws + 7168);
    float* scale2 = (float*)(ws + 9216);
    float* shift2 = (float*)(ws + 11264);
    unsigned short* wA   = (unsigned short*)(ws + 16384);              // 512*768*2  = 786432
    unsigned short* w3   = (unsigned short*)(ws + 802816);             // 9*512*512*2 = 4718592
    float*          x2   = (float*)         (ws + 5521408);            // 256*25600*4 = 26214400
    unsigned short* xcat = (unsigned short*)(ws + 31735808);           // 25600*768*2 = 39321600
    unsigned short* hpad = (unsigned short*)(ws + 71057408);           // 162*162*512*2 = 26873856

    reduce_kernel<<<C, 256, 0, stream>>>(x, avg, mx);
    mlp_select_kernel<<<1, C, 0, stream>>>(avg, mx, w_fc1, w_fc2, scales, idx, pos);
    affine_kernel<<<1, C, 0, stream>>>(b_dc1, bn2_g, bn2_b, bn2_m, bn2_v, scale2, shift2);
    wa_bf16_kernel<<<C, 256, 0, stream>>>(w_dc1, scales, pos, wA);
    w3_kernel<<<dim3(C, 9), 256, 0, stream>>>(w_dc2, w3);
    zero_border<<<161, 256, 0, stream>>>(hpad);
    dw_kernel<<<dim3(NPIX / 256, K), 256, 0, stream>>>(x, idx, w_ch, bn1_g, bn1_b, bn1_m, bn1_v, x2);
    transpose_kernel<<<dim3(NPIX / 32, 24), 256, 0, stream>>>(x, x2, xcat);
    conv1_mfma<<<dim3(HW, 4), 128, 0, stream>>>(xcat, wA, scale2, shift2, hpad);
    conv3_mfma<<<dim3(HW, 4), 128, 0, stream>>>(hpad, w3, b_dc2, out);
}